// Round 1
// baseline (1495.914 us; speedup 1.0000x reference)
//
#include <hip/hip_runtime.h>
#include <hip/hip_bf16.h>

typedef unsigned short u16;
typedef __attribute__((ext_vector_type(8))) short bf16x8;
typedef __attribute__((ext_vector_type(4))) float f32x4;

#define T_TOK 16384
#define H_DIM 2048
#define F_DIM 4096
#define E_NUM 8
#define CAPX  2048   // tokens per expert

__device__ __forceinline__ unsigned cvt2(float a, float b) {
    __hip_bfloat162 h = __float22bfloat162_rn(make_float2(a, b));
    union { __hip_bfloat162 h; unsigned u; } c; c.h = h; return c.u;
}
__device__ __forceinline__ u16 f2bf(float f) {
    __hip_bfloat16 h = __float2bfloat16(f);
    union { __hip_bfloat16 h; u16 u; } c; c.h = h; return c.u;
}
__device__ __forceinline__ float gelu_tanh(float x) {
    float x3 = x * x * x;
    float z = 0.7978845608028654f * (x + 0.044715f * x3);
    float e = __expf(2.0f * z);
    float t = 1.0f - 2.0f / (e + 1.0f);   // tanh(z)
    return 0.5f * x * (1.0f + t);
}

// C[M,N] = A[M,K] @ B[N,K]^T  per expert (both K-contiguous, "NT" GEMM).
// A: f32 (GEMM1 x) or bf16 (GEMM2 activations). B: f32 weights, converted
// to bf16 in the staging path. Output: gelu->bf16 (GEMM1) or f32 (GEMM2).
// 128x128 tile, BK=64, 256 threads = 4 waves (2x2), each wave 64x64 via
// 4x4 fragments of mfma_f32_16x16x32_bf16. LDS XOR-swizzled (T2, st-style).
template<bool A_BF16, bool GELU_BF16_OUT>
__global__ __launch_bounds__(256, 2)
void gemm_nt(const void* __restrict__ Av, const float* __restrict__ B,
             void* __restrict__ Cv, int Mpe, int N, int K,
             int mtpe, int ntpe) {
    __shared__ u16 As[128 * 64];
    __shared__ u16 Bs[128 * 64];

    const int tid  = threadIdx.x;
    const int lane = tid & 63;
    const int w    = tid >> 6;
    const int wr   = w >> 1, wc = w & 1;
    const int lr   = lane & 15;          // A-row / B-col / C-col within 16
    const int lkb  = (lane >> 4) << 3;   // k sub-offset: 0,8,16,24

    // XCD-aware bijective swizzle (grid % 8 == 0 by construction)
    const int nwg = gridDim.x;
    const int cpx = nwg >> 3;
    const int bid = blockIdx.x;
    const int wg  = (bid & 7) * cpx + (bid >> 3);

    const int tpe = mtpe * ntpe;
    const int e   = wg / tpe;
    const int rem = wg - e * tpe;
    const int mt  = rem / ntpe;
    const int nt  = rem - mt * ntpe;

    const size_t Abase = (size_t)e * Mpe * K + (size_t)mt * 128 * K;
    const size_t Bbase = (size_t)e * N   * K + (size_t)nt * 128 * K;

    // staging decomposition: 8 threads x 8 f32 per row, 32 rows/pass, 4 passes
    const int srow = tid >> 3;
    const int scol = (tid & 7) << 3;

    f32x4 acc[4][4] = {};

    const float* Af = (const float*)Av;
    const u16*   Ab = (const u16*)Av;

    for (int k0 = 0; k0 < K; k0 += 64) {
        #pragma unroll
        for (int p = 0; p < 4; ++p) {
            const int row = (p << 5) + srow;
            const int di  = (row << 6) + (scol ^ ((row & 7) << 3));  // 8-elem XOR swizzle
            if constexpr (A_BF16) {
                const u16* ap = Ab + Abase + (size_t)row * K + k0 + scol;
                *(uint4*)&As[di] = *(const uint4*)ap;
            } else {
                const float* ap = Af + Abase + (size_t)row * K + k0 + scol;
                float4 v0 = *(const float4*)ap;
                float4 v1 = *(const float4*)(ap + 4);
                uint4 pk;
                pk.x = cvt2(v0.x, v0.y); pk.y = cvt2(v0.z, v0.w);
                pk.z = cvt2(v1.x, v1.y); pk.w = cvt2(v1.z, v1.w);
                *(uint4*)&As[di] = pk;
            }
            {
                const float* bp = B + Bbase + (size_t)row * K + k0 + scol;
                float4 v0 = *(const float4*)bp;
                float4 v1 = *(const float4*)(bp + 4);
                uint4 pk;
                pk.x = cvt2(v0.x, v0.y); pk.y = cvt2(v0.z, v0.w);
                pk.z = cvt2(v1.x, v1.y); pk.w = cvt2(v1.z, v1.w);
                *(uint4*)&Bs[di] = pk;
            }
        }
        __syncthreads();

        #pragma unroll
        for (int ks = 0; ks < 2; ++ks) {
            const int kcol = (ks << 5) + lkb;
            bf16x8 af[4], bfv[4];
            #pragma unroll
            for (int m = 0; m < 4; ++m) {
                const int row = wr * 64 + m * 16 + lr;
                af[m] = *(const bf16x8*)&As[(row << 6) + (kcol ^ ((row & 7) << 3))];
            }
            #pragma unroll
            for (int n = 0; n < 4; ++n) {
                const int row = wc * 64 + n * 16 + lr;
                bfv[n] = *(const bf16x8*)&Bs[(row << 6) + (kcol ^ ((row & 7) << 3))];
            }
            #pragma unroll
            for (int m = 0; m < 4; ++m)
                #pragma unroll
                for (int n = 0; n < 4; ++n)
                    acc[m][n] = __builtin_amdgcn_mfma_f32_16x16x32_bf16(
                        af[m], bfv[n], acc[m][n], 0, 0, 0);
        }
        __syncthreads();
    }

    // epilogue: C/D layout col = lane&15, row = (lane>>4)*4 + reg  [m89/m91]
    const int r0 = (lane >> 4) << 2;
    if constexpr (GELU_BF16_OUT) {
        u16* Cb = (u16*)Cv;
        #pragma unroll
        for (int m = 0; m < 4; ++m) {
            #pragma unroll
            for (int n = 0; n < 4; ++n) {
                const int col = nt * 128 + wc * 64 + n * 16 + lr;
                #pragma unroll
                for (int j = 0; j < 4; ++j) {
                    const int row = mt * 128 + wr * 64 + m * 16 + r0 + j;
                    Cb[((size_t)e * Mpe + row) * N + col] =
                        f2bf(gelu_tanh(acc[m][n][j]));
                }
            }
        }
    } else {
        float* Cf = (float*)Cv;
        #pragma unroll
        for (int m = 0; m < 4; ++m) {
            #pragma unroll
            for (int n = 0; n < 4; ++n) {
                const int col = nt * 128 + wc * 64 + n * 16 + lr;
                #pragma unroll
                for (int j = 0; j < 4; ++j) {
                    const int row = mt * 128 + wr * 64 + m * 16 + r0 + j;
                    Cf[((size_t)e * Mpe + row) * N + col] = acc[m][n][j];
                }
            }
        }
    }
}

extern "C" void kernel_launch(void* const* d_in, const int* in_sizes, int n_in,
                              void* d_out, int out_size, void* d_ws, size_t ws_size,
                              hipStream_t stream) {
    const float* x  = (const float*)d_in[0];   // (T, H)
    const float* w1 = (const float*)d_in[1];   // (E, F, H)
    const float* w2 = (const float*)d_in[2];   // (E, H, F)
    // d_in[3] = splits (static balanced, unused)
    float* out = (float*)d_out;                // (T, H) f32
    u16* a_ws = (u16*)d_ws;                    // (T, F) bf16 intermediate, 128 MB

    dim3 blk(256);
    // GEMM1: per expert M=2048, N=F=4096, K=H=2048 -> 16*32 tiles * 8 = 4096
    const int grid1 = E_NUM * (CAPX / 128) * (F_DIM / 128);
    gemm_nt<false, true><<<grid1, blk, 0, stream>>>(
        (const void*)x, w1, (void*)a_ws, CAPX, F_DIM, H_DIM,
        CAPX / 128, F_DIM / 128);

    // GEMM2: per expert M=2048, N=H=2048, K=F=4096 -> 16*16 tiles * 8 = 2048
    const int grid2 = E_NUM * (CAPX / 128) * (H_DIM / 128);
    gemm_nt<true, false><<<grid2, blk, 0, stream>>>(
        (const void*)a_ws, w2, (void*)out, CAPX, H_DIM, F_DIM,
        CAPX / 128, H_DIM / 128);
}

// Round 2
// 905.035 us; speedup vs baseline: 1.6529x; 1.6529x over previous
//
#include <hip/hip_runtime.h>
#include <hip/hip_bf16.h>

typedef unsigned short u16;
typedef __attribute__((ext_vector_type(8))) short bf16x8;
typedef __attribute__((ext_vector_type(4))) float f32x4;

#define T_TOK 16384
#define H_DIM 2048
#define F_DIM 4096
#define E_NUM 8
#define CAPX  2048   // tokens per expert

__device__ __forceinline__ unsigned cvt2(float a, float b) {
    __hip_bfloat162 h = __float22bfloat162_rn(make_float2(a, b));
    union { __hip_bfloat162 h; unsigned u; } c; c.h = h; return c.u;
}
__device__ __forceinline__ u16 f2bf(float f) {
    __hip_bfloat16 h = __float2bfloat16(f);
    union { __hip_bfloat16 h; u16 u; } c; c.h = h; return c.u;
}
__device__ __forceinline__ float gelu_tanh(float x) {
    float x3 = x * x * x;
    float z = 0.7978845608028654f * (x + 0.044715f * x3);
    float e = __expf(2.0f * z);
    float t = 1.0f - 2.0f / (e + 1.0f);   // tanh(z)
    return 0.5f * x * (1.0f + t);
}

__device__ __forceinline__ void gload_lds16(const void* g, void* l) {
    __builtin_amdgcn_global_load_lds(
        (const __attribute__((address_space(1))) void*)g,
        (__attribute__((address_space(3))) void*)l,
        16, 0, 0);
}

// ---------------------------------------------------------------------------
// f32 -> bf16 conversion pre-pass (memory-bound, vectorized 8 elems/thread)
// ---------------------------------------------------------------------------
__global__ void cvt_f32_bf16(const float* __restrict__ in, u16* __restrict__ out,
                             long n) {
    long i = (((long)blockIdx.x * blockDim.x) + threadIdx.x) << 3;
    const long stride = ((long)gridDim.x * blockDim.x) << 3;
    for (; i < n; i += stride) {
        float4 v0 = *(const float4*)(in + i);
        float4 v1 = *(const float4*)(in + i + 4);
        uint4 pk;
        pk.x = cvt2(v0.x, v0.y); pk.y = cvt2(v0.z, v0.w);
        pk.z = cvt2(v1.x, v1.y); pk.w = cvt2(v1.z, v1.w);
        *(uint4*)(out + i) = pk;
    }
}

// ---------------------------------------------------------------------------
// FAST PATH: pure-bf16 NT GEMM, m97 structure: 128x128 tile, BK=64,
// global_load_lds width=16 into LINEAR LDS, 2 barriers/K-step,
// 4 waves (2x2), 4x4 frags of mfma_f32_16x16x32_bf16 per wave.
// C[M,N] = A[M,K] @ B[N,K]^T per expert.
// ---------------------------------------------------------------------------
template<bool GELU_BF16_OUT>
__global__ __launch_bounds__(256, 2)
void gemm_lds(const u16* __restrict__ A, const u16* __restrict__ B,
              void* __restrict__ Cv, int Mpe, int N, int K,
              int mtpe, int ntpe) {
    __shared__ u16 As[128 * 64];
    __shared__ u16 Bs[128 * 64];

    const int tid  = threadIdx.x;
    const int lane = tid & 63;
    const int wid  = tid >> 6;
    const int wr   = wid >> 1, wc = wid & 1;
    const int lr   = lane & 15;          // row/col within 16
    const int lkb  = (lane >> 4) << 3;   // k sub-offset: 0,8,16,24

    // XCD-aware bijective swizzle (grid % 8 == 0 by construction)
    const int nwg = gridDim.x;
    const int cpx = nwg >> 3;
    const int bid = blockIdx.x;
    const int wg  = (bid & 7) * cpx + (bid >> 3);

    const int tpe = mtpe * ntpe;
    const int e   = wg / tpe;
    const int rem = wg - e * tpe;
    const int mt  = rem / ntpe;
    const int nt  = rem - mt * ntpe;

    const u16* Abase = A + (size_t)e * Mpe * K + (size_t)mt * 128 * K;
    const u16* Bbase = B + (size_t)e * N   * K + (size_t)nt * 128 * K;

    // staging: tile is 128 rows x 128 bytes (64 bf16), linear in LDS.
    // per gload_lds inst: wave writes 1024 B at (p*4096 + wid*1024);
    // lane's chunk c = p*4096 + wid*1024 + lane*16 -> row = c>>7, kb = c&127.
    const int srow = (wid << 3) + (lane >> 3);  // rows 0..31 (phase adds 32)
    const int skb  = (lane & 7) << 4;           // byte offset within row

    f32x4 acc[4][4] = {};

    for (int k0 = 0; k0 < K; k0 += 64) {
        #pragma unroll
        for (int p = 0; p < 4; ++p) {
            const int row = (p << 5) + srow;
            const char* ga = (const char*)(Abase + (size_t)row * K + k0) + skb;
            const char* gb = (const char*)(Bbase + (size_t)row * K + k0) + skb;
            char* la = (char*)As + (p << 12) + (wid << 10);
            char* lb = (char*)Bs + (p << 12) + (wid << 10);
            gload_lds16(ga, la);
            gload_lds16(gb, lb);
        }
        __syncthreads();   // compiler emits vmcnt(0) before s_barrier

        #pragma unroll
        for (int ks = 0; ks < 2; ++ks) {
            const int kcol = (ks << 5) + lkb;
            bf16x8 af[4], bfv[4];
            #pragma unroll
            for (int m = 0; m < 4; ++m)
                af[m] = *(const bf16x8*)&As[(wr * 64 + m * 16 + lr) * 64 + kcol];
            #pragma unroll
            for (int n = 0; n < 4; ++n)
                bfv[n] = *(const bf16x8*)&Bs[(wc * 64 + n * 16 + lr) * 64 + kcol];
            #pragma unroll
            for (int m = 0; m < 4; ++m)
                #pragma unroll
                for (int n = 0; n < 4; ++n)
                    acc[m][n] = __builtin_amdgcn_mfma_f32_16x16x32_bf16(
                        af[m], bfv[n], acc[m][n], 0, 0, 0);
        }
        __syncthreads();
    }

    // epilogue: C/D layout col = lane&15, row = (lane>>4)*4 + reg  [m89/m91]
    const int r0 = (lane >> 4) << 2;
    if constexpr (GELU_BF16_OUT) {
        u16* Cb = (u16*)Cv;
        #pragma unroll
        for (int m = 0; m < 4; ++m)
            #pragma unroll
            for (int n = 0; n < 4; ++n) {
                const int col = nt * 128 + wc * 64 + n * 16 + lr;
                #pragma unroll
                for (int j = 0; j < 4; ++j) {
                    const int row = mt * 128 + wr * 64 + m * 16 + r0 + j;
                    Cb[((size_t)e * Mpe + row) * N + col] =
                        f2bf(gelu_tanh(acc[m][n][j]));
                }
            }
    } else {
        float* Cf = (float*)Cv;
        #pragma unroll
        for (int m = 0; m < 4; ++m)
            #pragma unroll
            for (int n = 0; n < 4; ++n) {
                const int col = nt * 128 + wc * 64 + n * 16 + lr;
                #pragma unroll
                for (int j = 0; j < 4; ++j) {
                    const int row = mt * 128 + wr * 64 + m * 16 + r0 + j;
                    Cf[((size_t)e * Mpe + row) * N + col] = acc[m][n][j];
                }
            }
    }
}

// ---------------------------------------------------------------------------
// FALLBACK (round-1): reg-staged with in-flight f32->bf16 conversion.
// Used only if ws_size can't hold the bf16 copies.
// ---------------------------------------------------------------------------
template<bool A_BF16, bool GELU_BF16_OUT>
__global__ __launch_bounds__(256, 2)
void gemm_nt(const void* __restrict__ Av, const float* __restrict__ B,
             void* __restrict__ Cv, int Mpe, int N, int K,
             int mtpe, int ntpe) {
    __shared__ u16 As[128 * 64];
    __shared__ u16 Bs[128 * 64];

    const int tid  = threadIdx.x;
    const int lane = tid & 63;
    const int w    = tid >> 6;
    const int wr   = w >> 1, wc = w & 1;
    const int lr   = lane & 15;
    const int lkb  = (lane >> 4) << 3;

    const int nwg = gridDim.x;
    const int cpx = nwg >> 3;
    const int bid = blockIdx.x;
    const int wg  = (bid & 7) * cpx + (bid >> 3);

    const int tpe = mtpe * ntpe;
    const int e   = wg / tpe;
    const int rem = wg - e * tpe;
    const int mt  = rem / ntpe;
    const int nt  = rem - mt * ntpe;

    const size_t Abase = (size_t)e * Mpe * K + (size_t)mt * 128 * K;
    const size_t Bbase = (size_t)e * N   * K + (size_t)nt * 128 * K;

    const int srow = tid >> 3;
    const int scol = (tid & 7) << 3;

    f32x4 acc[4][4] = {};

    const float* Af = (const float*)Av;
    const u16*   Ab = (const u16*)Av;

    for (int k0 = 0; k0 < K; k0 += 64) {
        #pragma unroll
        for (int p = 0; p < 4; ++p) {
            const int row = (p << 5) + srow;
            const int di  = (row << 6) + (scol ^ ((row & 7) << 3));
            if constexpr (A_BF16) {
                const u16* ap = Ab + Abase + (size_t)row * K + k0 + scol;
                *(uint4*)&As[di] = *(const uint4*)ap;
            } else {
                const float* ap = Af + Abase + (size_t)row * K + k0 + scol;
                float4 v0 = *(const float4*)ap;
                float4 v1 = *(const float4*)(ap + 4);
                uint4 pk;
                pk.x = cvt2(v0.x, v0.y); pk.y = cvt2(v0.z, v0.w);
                pk.z = cvt2(v1.x, v1.y); pk.w = cvt2(v1.z, v1.w);
                *(uint4*)&As[di] = pk;
            }
            {
                const float* bp = B + Bbase + (size_t)row * K + k0 + scol;
                float4 v0 = *(const float4*)bp;
                float4 v1 = *(const float4*)(bp + 4);
                uint4 pk;
                pk.x = cvt2(v0.x, v0.y); pk.y = cvt2(v0.z, v0.w);
                pk.z = cvt2(v1.x, v1.y); pk.w = cvt2(v1.z, v1.w);
                *(uint4*)&Bs[di] = pk;
            }
        }
        __syncthreads();

        #pragma unroll
        for (int ks = 0; ks < 2; ++ks) {
            const int kcol = (ks << 5) + lkb;
            bf16x8 af[4], bfv[4];
            #pragma unroll
            for (int m = 0; m < 4; ++m) {
                const int row = wr * 64 + m * 16 + lr;
                af[m] = *(const bf16x8*)&As[(row << 6) + (kcol ^ ((row & 7) << 3))];
            }
            #pragma unroll
            for (int n = 0; n < 4; ++n) {
                const int row = wc * 64 + n * 16 + lr;
                bfv[n] = *(const bf16x8*)&Bs[(row << 6) + (kcol ^ ((row & 7) << 3))];
            }
            #pragma unroll
            for (int m = 0; m < 4; ++m)
                #pragma unroll
                for (int n = 0; n < 4; ++n)
                    acc[m][n] = __builtin_amdgcn_mfma_f32_16x16x32_bf16(
                        af[m], bfv[n], acc[m][n], 0, 0, 0);
        }
        __syncthreads();
    }

    const int r0 = (lane >> 4) << 2;
    if constexpr (GELU_BF16_OUT) {
        u16* Cb = (u16*)Cv;
        #pragma unroll
        for (int m = 0; m < 4; ++m)
            #pragma unroll
            for (int n = 0; n < 4; ++n) {
                const int col = nt * 128 + wc * 64 + n * 16 + lr;
                #pragma unroll
                for (int j = 0; j < 4; ++j) {
                    const int row = mt * 128 + wr * 64 + m * 16 + r0 + j;
                    Cb[((size_t)e * Mpe + row) * N + col] =
                        f2bf(gelu_tanh(acc[m][n][j]));
                }
            }
    } else {
        float* Cf = (float*)Cv;
        #pragma unroll
        for (int m = 0; m < 4; ++m)
            #pragma unroll
            for (int n = 0; n < 4; ++n) {
                const int col = nt * 128 + wc * 64 + n * 16 + lr;
                #pragma unroll
                for (int j = 0; j < 4; ++j) {
                    const int row = mt * 128 + wr * 64 + m * 16 + r0 + j;
                    Cf[((size_t)e * Mpe + row) * N + col] = acc[m][n][j];
                }
            }
    }
}

extern "C" void kernel_launch(void* const* d_in, const int* in_sizes, int n_in,
                              void* d_out, int out_size, void* d_ws, size_t ws_size,
                              hipStream_t stream) {
    const float* x  = (const float*)d_in[0];   // (T, H)
    const float* w1 = (const float*)d_in[1];   // (E, F, H)
    const float* w2 = (const float*)d_in[2];   // (E, H, F)
    float* out = (float*)d_out;                // (T, H) f32

    // ws layout (bytes):
    //   [0,              134217728)  a_ws : bf16 (T, F) activations
    //   [134217728,      201326592)  xb   : bf16 (T, H)
    //   [201326592,      335544320)  w1b  : bf16 (E, F, H)
    //   [335544320,      469762048)  w2b  : bf16 (E, H, F)
    const size_t A_WS_B = (size_t)T_TOK * F_DIM * 2;               // 134217728
    const size_t XB_B   = (size_t)T_TOK * H_DIM * 2;               //  67108864
    const size_t W_B    = (size_t)E_NUM * F_DIM * H_DIM * 2;       // 134217728
    const size_t NEED   = A_WS_B + XB_B + 2 * W_B;                 // 469762048

    u16* a_ws = (u16*)d_ws;
    dim3 blk(256);

    if (ws_size >= NEED) {
        u16* xb  = (u16*)((char*)d_ws + A_WS_B);
        u16* w1b = (u16*)((char*)d_ws + A_WS_B + XB_B);
        u16* w2b = (u16*)((char*)d_ws + A_WS_B + XB_B + W_B);

        cvt_f32_bf16<<<2048, blk, 0, stream>>>(x,  xb,  (long)T_TOK * H_DIM);
        cvt_f32_bf16<<<2048, blk, 0, stream>>>(w1, w1b, (long)E_NUM * F_DIM * H_DIM);
        cvt_f32_bf16<<<2048, blk, 0, stream>>>(w2, w2b, (long)E_NUM * H_DIM * F_DIM);

        const int grid1 = E_NUM * (CAPX / 128) * (F_DIM / 128);  // 4096
        gemm_lds<true><<<grid1, blk, 0, stream>>>(
            xb, w1b, (void*)a_ws, CAPX, F_DIM, H_DIM, CAPX / 128, F_DIM / 128);

        const int grid2 = E_NUM * (CAPX / 128) * (H_DIM / 128);  // 2048
        gemm_lds<false><<<grid2, blk, 0, stream>>>(
            a_ws, w2b, (void*)out, CAPX, H_DIM, F_DIM, CAPX / 128, H_DIM / 128);
    } else {
        // fallback: round-1 reg-staged path (needs only a_ws)
        const int grid1 = E_NUM * (CAPX / 128) * (F_DIM / 128);
        gemm_nt<false, true><<<grid1, blk, 0, stream>>>(
            (const void*)x, w1, (void*)a_ws, CAPX, F_DIM, H_DIM,
            CAPX / 128, F_DIM / 128);

        const int grid2 = E_NUM * (CAPX / 128) * (H_DIM / 128);
        gemm_nt<true, false><<<grid2, blk, 0, stream>>>(
            (const void*)a_ws, w2, (void*)out, CAPX, H_DIM, F_DIM,
            CAPX / 128, H_DIM / 128);
    }
}

// Round 3
// 703.516 us; speedup vs baseline: 2.1263x; 1.2864x over previous
//
#include <hip/hip_runtime.h>
#include <hip/hip_bf16.h>

typedef unsigned short u16;
typedef __attribute__((ext_vector_type(8))) short bf16x8;
typedef __attribute__((ext_vector_type(4))) float f32x4;

#define T_TOK 16384
#define H_DIM 2048
#define F_DIM 4096
#define E_NUM 8
#define CAPX  2048   // tokens per expert

__device__ __forceinline__ unsigned cvt2(float a, float b) {
    __hip_bfloat162 h = __float22bfloat162_rn(make_float2(a, b));
    union { __hip_bfloat162 h; unsigned u; } c; c.h = h; return c.u;
}
__device__ __forceinline__ u16 f2bf(float f) {
    __hip_bfloat16 h = __float2bfloat16(f);
    union { __hip_bfloat16 h; u16 u; } c; c.h = h; return c.u;
}
__device__ __forceinline__ float gelu_tanh(float x) {
    float x3 = x * x * x;
    float z = 0.7978845608028654f * (x + 0.044715f * x3);
    float e = __expf(2.0f * z);
    float t = 1.0f - 2.0f / (e + 1.0f);   // tanh(z)
    return 0.5f * x * (1.0f + t);
}

__device__ __forceinline__ void gload_lds16(const void* g, void* l) {
    __builtin_amdgcn_global_load_lds(
        (const __attribute__((address_space(1))) void*)g,
        (__attribute__((address_space(3))) void*)l,
        16, 0, 0);
}

// ---------------------------------------------------------------------------
// f32 -> bf16 conversion pre-pass
// ---------------------------------------------------------------------------
__global__ void cvt_f32_bf16(const float* __restrict__ in, u16* __restrict__ out,
                             long n) {
    long i = (((long)blockIdx.x * blockDim.x) + threadIdx.x) << 3;
    const long stride = ((long)gridDim.x * blockDim.x) << 3;
    for (; i < n; i += stride) {
        float4 v0 = *(const float4*)(in + i);
        float4 v1 = *(const float4*)(in + i + 4);
        uint4 pk;
        pk.x = cvt2(v0.x, v0.y); pk.y = cvt2(v0.z, v0.w);
        pk.z = cvt2(v1.x, v1.y); pk.w = cvt2(v1.z, v1.w);
        *(uint4*)(out + i) = pk;
    }
}

// ---------------------------------------------------------------------------
// 256x256 8-phase bf16 NT GEMM (T2+T3+T4+T5), plain HIP.
// C[M,N] = A[M,K] @ B[N,K]^T per expert.
// 512 thr = 8 waves (2M x 4N); per-wave 128x64 out = acc[8][4] f32x4.
// BK=64 split into 2 K-halves of 32; LDS = 2 buf x (A 32K + B 32K) = 128 KiB.
// Stage granularity = half-tile (256 rows x 32 k) = 2 x global_load_lds/thr.
// Rotation (iter computes tiles t,t+1; t even -> buf0):
//   p1:A1(t+1)->b1  p2:B0(t+2)->b0  p3:A0(t+2)->b0  p4:B1(t+2)->b0 +vmcnt(6)
//   p5:A1(t+2)->b0  p6:B0(t+3)->b1  p7:A0(t+3)->b1  p8:B1(t+3)->b1 +vmcnt(6)
// Phase p=(ks,Mh) consumes only K-half ks => every stage targets a slot whose
// readers finished >=1 barrier earlier (WAR-safe by construction).
// Swizzle: LDS 16B-slot' = slot ^ ((row>>1)&3); linear LDS dest + pre-swizzled
// global source (rule 21), same involution on ds_read side.
// ---------------------------------------------------------------------------
template<bool GELU_BF16_OUT>
__global__ __launch_bounds__(512, 2)
void gemm8p(const u16* __restrict__ A, const u16* __restrict__ B,
            void* __restrict__ Cv, int Mpe, int N, int K,
            int mtpe, int ntpe) {
    __shared__ uint4 lds4[8192];          // 128 KiB
    char* ldsb = (char*)lds4;

    const int tid  = threadIdx.x;
    const int lane = tid & 63;
    const int wid  = tid >> 6;
    const int wm   = wid >> 2;            // 0..1
    const int wn   = wid & 3;             // 0..3
    const int lr   = lane & 15;

    // XCD-aware bijective swizzle (grid % 8 == 0)
    const int nwg = gridDim.x;
    const int cpx = nwg >> 3;
    const int bid = blockIdx.x;
    const int wg  = (bid & 7) * cpx + (bid >> 3);

    const int tpe = mtpe * ntpe;
    const int e   = wg / tpe;
    const int rem = wg - e * tpe;
    const int mt  = rem / ntpe;
    const int nt  = rem - mt * ntpe;

    const u16* Abase = A + (size_t)e * Mpe * K + (size_t)mt * 256 * K;
    const u16* Bbase = B + (size_t)e * N   * K + (size_t)nt * 256 * K;

    // staging per-thread constants: dest (row,slot) <- global (row, slot^xor)
    const int srow = tid >> 2;                      // l=0 row; l=1 adds 128
    const int sx   = (tid & 3) ^ ((tid >> 3) & 3);  // pre-swizzled source slot
    const size_t soff0 = (size_t)srow * K + (size_t)sx * 8;
    const size_t soff1 = (size_t)(srow + 128) * K + (size_t)sx * 8;

    // read-side per-thread byte offsets (swizzled slot)
    const int slotp = (((lane >> 4) ^ ((lr >> 1) & 3)) << 4);
    const int aoffb = ((wm * 128 + lr) << 6) + slotp;
    const int boffb = ((wn * 64  + lr) << 6) + slotp;

    const int NT = K >> 6;   // K-tiles (even for K=2048/4096)

    f32x4 acc[8][4] = {};
    bf16x8 af[4], bf[4];

#define STAGE(OP, KH, BUF, TILE)  do {                                        \
    int tc_ = (TILE) < NT ? (TILE) : (TILE) - 2;                              \
    const u16* gb_ = ((OP) ? Bbase : Abase) + (size_t)tc_ * 64 + (KH) * 32;   \
    char* db_ = ldsb + (OP) * 65536 + (BUF) * 32768 + (KH) * 16384 + (wid << 10); \
    gload_lds16(gb_ + soff0, db_);                                            \
    gload_lds16(gb_ + soff1, db_ + 8192);                                     \
} while (0)

#define READ_A(BUF, KS, MH) do {                                              \
    const char* ab_ = ldsb + (BUF) * 32768 + (KS) * 16384 + aoffb + (MH) * 4096; \
    af[0] = *(const bf16x8*)(ab_);                                            \
    af[1] = *(const bf16x8*)(ab_ + 1024);                                     \
    af[2] = *(const bf16x8*)(ab_ + 2048);                                     \
    af[3] = *(const bf16x8*)(ab_ + 3072);                                     \
} while (0)

#define READ_B(BUF, KS) do {                                                  \
    const char* bb_ = ldsb + 65536 + (BUF) * 32768 + (KS) * 16384 + boffb;    \
    bf[0] = *(const bf16x8*)(bb_);                                            \
    bf[1] = *(const bf16x8*)(bb_ + 1024);                                     \
    bf[2] = *(const bf16x8*)(bb_ + 2048);                                     \
    bf[3] = *(const bf16x8*)(bb_ + 3072);                                     \
} while (0)

#define FENCE() do { __builtin_amdgcn_sched_barrier(0);                       \
                     asm volatile("" ::: "memory"); } while (0)
#define BAR()   do { FENCE(); __builtin_amdgcn_s_barrier(); FENCE(); } while (0)
#define VM6()   do { asm volatile("s_waitcnt vmcnt(6)" ::: "memory"); } while (0)

#define MFMA16(MH) do {                                                       \
    __builtin_amdgcn_s_setprio(1);                                            \
    _Pragma("unroll")                                                         \
    for (int i_ = 0; i_ < 4; ++i_) {                                          \
        _Pragma("unroll")                                                     \
        for (int n_ = 0; n_ < 4; ++n_)                                        \
            acc[(MH)*4 + i_][n_] = __builtin_amdgcn_mfma_f32_16x16x32_bf16(   \
                af[i_], bf[n_], acc[(MH)*4 + i_][n_], 0, 0, 0);               \
    }                                                                         \
    __builtin_amdgcn_s_setprio(0);                                            \
} while (0)

    // prologue: 7 halves in steady-state order, then vmcnt(6) => tile0 landed
    STAGE(1, 0, 0, 0);  // B0(0)
    STAGE(0, 0, 0, 0);  // A0(0)
    STAGE(1, 1, 0, 0);  // B1(0)
    STAGE(0, 1, 0, 0);  // A1(0)
    STAGE(1, 0, 1, 1);  // B0(1)
    STAGE(0, 0, 1, 1);  // A0(1)
    STAGE(1, 1, 1, 1);  // B1(1)
    VM6();
    BAR();

    for (int t = 0; t < NT; t += 2) {
        // ---- tile t (buf0) ----
        // p1: (ks0, Mh0)
        READ_A(0, 0, 0); READ_B(0, 0);
        STAGE(0, 1, 1, t + 1);
        BAR(); MFMA16(0); BAR();
        // p2: (ks0, Mh1)
        READ_A(0, 0, 1);
        STAGE(1, 0, 0, t + 2);
        BAR(); MFMA16(1); BAR();
        // p3: (ks1, Mh0)
        READ_A(0, 1, 0); READ_B(0, 1);
        STAGE(0, 0, 0, t + 2);
        BAR(); MFMA16(0); BAR();
        // p4: (ks1, Mh1)
        READ_A(0, 1, 1);
        STAGE(1, 1, 0, t + 2);
        VM6();
        BAR(); MFMA16(1); BAR();
        // ---- tile t+1 (buf1) ----
        // p5: (ks0, Mh0)
        READ_A(1, 0, 0); READ_B(1, 0);
        STAGE(0, 1, 0, t + 2);
        BAR(); MFMA16(0); BAR();
        // p6: (ks0, Mh1)
        READ_A(1, 0, 1);
        STAGE(1, 0, 1, t + 3);
        BAR(); MFMA16(1); BAR();
        // p7: (ks1, Mh0)
        READ_A(1, 1, 0); READ_B(1, 1);
        STAGE(0, 0, 1, t + 3);
        BAR(); MFMA16(0); BAR();
        // p8: (ks1, Mh1)
        READ_A(1, 1, 1);
        STAGE(1, 1, 1, t + 3);
        VM6();
        BAR(); MFMA16(1); BAR();
    }

#undef STAGE
#undef READ_A
#undef READ_B
#undef FENCE
#undef BAR
#undef VM6
#undef MFMA16

    // epilogue: C/D layout col = lane&15, row = (lane>>4)*4 + reg
    const int r0 = (lane >> 4) << 2;
    if constexpr (GELU_BF16_OUT) {
        u16* Cb = (u16*)Cv;
        #pragma unroll
        for (int m = 0; m < 8; ++m)
            #pragma unroll
            for (int n = 0; n < 4; ++n) {
                const int col = nt * 256 + wn * 64 + n * 16 + lr;
                #pragma unroll
                for (int j = 0; j < 4; ++j) {
                    const int row = mt * 256 + wm * 128 + m * 16 + r0 + j;
                    Cb[((size_t)e * Mpe + row) * N + col] =
                        f2bf(gelu_tanh(acc[m][n][j]));
                }
            }
    } else {
        float* Cf = (float*)Cv;
        #pragma unroll
        for (int m = 0; m < 8; ++m)
            #pragma unroll
            for (int n = 0; n < 4; ++n) {
                const int col = nt * 256 + wn * 64 + n * 16 + lr;
                #pragma unroll
                for (int j = 0; j < 4; ++j) {
                    const int row = mt * 256 + wm * 128 + m * 16 + r0 + j;
                    Cf[((size_t)e * Mpe + row) * N + col] = acc[m][n][j];
                }
            }
    }
}

// ---------------------------------------------------------------------------
// FALLBACK (round-1): reg-staged with in-flight f32->bf16 conversion.
// ---------------------------------------------------------------------------
template<bool A_BF16, bool GELU_BF16_OUT>
__global__ __launch_bounds__(256, 2)
void gemm_nt(const void* __restrict__ Av, const float* __restrict__ B,
             void* __restrict__ Cv, int Mpe, int N, int K,
             int mtpe, int ntpe) {
    __shared__ u16 As[128 * 64];
    __shared__ u16 Bs[128 * 64];

    const int tid  = threadIdx.x;
    const int lane = tid & 63;
    const int w    = tid >> 6;
    const int wr   = w >> 1, wc = w & 1;
    const int lr   = lane & 15;
    const int lkb  = (lane >> 4) << 3;

    const int nwg = gridDim.x;
    const int cpx = nwg >> 3;
    const int bid = blockIdx.x;
    const int wg  = (bid & 7) * cpx + (bid >> 3);

    const int tpe = mtpe * ntpe;
    const int e   = wg / tpe;
    const int rem = wg - e * tpe;
    const int mt  = rem / ntpe;
    const int nt  = rem - mt * ntpe;

    const size_t Abase = (size_t)e * Mpe * K + (size_t)mt * 128 * K;
    const size_t Bbase = (size_t)e * N   * K + (size_t)nt * 128 * K;

    const int srow = tid >> 3;
    const int scol = (tid & 7) << 3;

    f32x4 acc[4][4] = {};

    const float* Af = (const float*)Av;
    const u16*   Ab = (const u16*)Av;

    for (int k0 = 0; k0 < K; k0 += 64) {
        #pragma unroll
        for (int p = 0; p < 4; ++p) {
            const int row = (p << 5) + srow;
            const int di  = (row << 6) + (scol ^ ((row & 7) << 3));
            if constexpr (A_BF16) {
                const u16* ap = Ab + Abase + (size_t)row * K + k0 + scol;
                *(uint4*)&As[di] = *(const uint4*)ap;
            } else {
                const float* ap = Af + Abase + (size_t)row * K + k0 + scol;
                float4 v0 = *(const float4*)ap;
                float4 v1 = *(const float4*)(ap + 4);
                uint4 pk;
                pk.x = cvt2(v0.x, v0.y); pk.y = cvt2(v0.z, v0.w);
                pk.z = cvt2(v1.x, v1.y); pk.w = cvt2(v1.z, v1.w);
                *(uint4*)&As[di] = pk;
            }
            {
                const float* bp = B + Bbase + (size_t)row * K + k0 + scol;
                float4 v0 = *(const float4*)bp;
                float4 v1 = *(const float4*)(bp + 4);
                uint4 pk;
                pk.x = cvt2(v0.x, v0.y); pk.y = cvt2(v0.z, v0.w);
                pk.z = cvt2(v1.x, v1.y); pk.w = cvt2(v1.z, v1.w);
                *(uint4*)&Bs[di] = pk;
            }
        }
        __syncthreads();

        #pragma unroll
        for (int ks = 0; ks < 2; ++ks) {
            const int kcol = (ks << 5) + lkb;
            bf16x8 af[4], bfv[4];
            #pragma unroll
            for (int m = 0; m < 4; ++m) {
                const int row = wr * 64 + m * 16 + lr;
                af[m] = *(const bf16x8*)&As[(row << 6) + (kcol ^ ((row & 7) << 3))];
            }
            #pragma unroll
            for (int n = 0; n < 4; ++n) {
                const int row = wc * 64 + n * 16 + lr;
                bfv[n] = *(const bf16x8*)&Bs[(row << 6) + (kcol ^ ((row & 7) << 3))];
            }
            #pragma unroll
            for (int m = 0; m < 4; ++m)
                #pragma unroll
                for (int n = 0; n < 4; ++n)
                    acc[m][n] = __builtin_amdgcn_mfma_f32_16x16x32_bf16(
                        af[m], bfv[n], acc[m][n], 0, 0, 0);
        }
        __syncthreads();
    }

    const int r0 = (lane >> 4) << 2;
    if constexpr (GELU_BF16_OUT) {
        u16* Cb = (u16*)Cv;
        #pragma unroll
        for (int m = 0; m < 4; ++m)
            #pragma unroll
            for (int n = 0; n < 4; ++n) {
                const int col = nt * 128 + wc * 64 + n * 16 + lr;
                #pragma unroll
                for (int j = 0; j < 4; ++j) {
                    const int row = mt * 128 + wr * 64 + m * 16 + r0 + j;
                    Cb[((size_t)e * Mpe + row) * N + col] =
                        f2bf(gelu_tanh(acc[m][n][j]));
                }
            }
    } else {
        float* Cf = (float*)Cv;
        #pragma unroll
        for (int m = 0; m < 4; ++m)
            #pragma unroll
            for (int n = 0; n < 4; ++n) {
                const int col = nt * 128 + wc * 64 + n * 16 + lr;
                #pragma unroll
                for (int j = 0; j < 4; ++j) {
                    const int row = mt * 128 + wr * 64 + m * 16 + r0 + j;
                    Cf[((size_t)e * Mpe + row) * N + col] = acc[m][n][j];
                }
            }
    }
}

extern "C" void kernel_launch(void* const* d_in, const int* in_sizes, int n_in,
                              void* d_out, int out_size, void* d_ws, size_t ws_size,
                              hipStream_t stream) {
    const float* x  = (const float*)d_in[0];   // (T, H)
    const float* w1 = (const float*)d_in[1];   // (E, F, H)
    const float* w2 = (const float*)d_in[2];   // (E, H, F)
    float* out = (float*)d_out;                // (T, H) f32

    const size_t A_WS_B = (size_t)T_TOK * F_DIM * 2;               // 134217728
    const size_t XB_B   = (size_t)T_TOK * H_DIM * 2;               //  67108864
    const size_t W_B    = (size_t)E_NUM * F_DIM * H_DIM * 2;       // 134217728
    const size_t NEED   = A_WS_B + XB_B + 2 * W_B;                 // 469762048

    u16* a_ws = (u16*)d_ws;
    dim3 blk(256);

    if (ws_size >= NEED) {
        u16* xb  = (u16*)((char*)d_ws + A_WS_B);
        u16* w1b = (u16*)((char*)d_ws + A_WS_B + XB_B);
        u16* w2b = (u16*)((char*)d_ws + A_WS_B + XB_B + W_B);

        cvt_f32_bf16<<<2048, blk, 0, stream>>>(x,  xb,  (long)T_TOK * H_DIM);
        cvt_f32_bf16<<<2048, blk, 0, stream>>>(w1, w1b, (long)E_NUM * F_DIM * H_DIM);
        cvt_f32_bf16<<<2048, blk, 0, stream>>>(w2, w2b, (long)E_NUM * H_DIM * F_DIM);

        // GEMM1: per expert M=2048, N=4096, K=2048; 256^2 tiles -> 8*8*16=1024
        const int grid1 = E_NUM * (CAPX / 256) * (F_DIM / 256);
        gemm8p<true><<<grid1, dim3(512), 0, stream>>>(
            xb, w1b, (void*)a_ws, CAPX, F_DIM, H_DIM, CAPX / 256, F_DIM / 256);

        // GEMM2: per expert M=2048, N=2048, K=4096; -> 8*8*8=512
        const int grid2 = E_NUM * (CAPX / 256) * (H_DIM / 256);
        gemm8p<false><<<grid2, dim3(512), 0, stream>>>(
            a_ws, w2b, (void*)out, CAPX, H_DIM, F_DIM, CAPX / 256, H_DIM / 256);
    } else {
        const int grid1 = E_NUM * (CAPX / 128) * (F_DIM / 128);
        gemm_nt<false, true><<<grid1, blk, 0, stream>>>(
            (const void*)x, w1, (void*)a_ws, CAPX, F_DIM, H_DIM,
            CAPX / 128, F_DIM / 128);

        const int grid2 = E_NUM * (CAPX / 128) * (H_DIM / 128);
        gemm_nt<true, false><<<grid2, blk, 0, stream>>>(
            (const void*)a_ws, w2, (void*)out, CAPX, H_DIM, F_DIM,
            CAPX / 128, H_DIM / 128);
    }
}